// Round 10
// baseline (378.139 us; speedup 1.0000x reference)
//
#include <hip/hip_runtime.h>
#include <hip/hip_bf16.h>
#include <stdint.h>

#define NB 2
#define NH 16
#define LT 2048
#define LS 2048
#define DIM 1024
#define HD 64

typedef __attribute__((ext_vector_type(4))) float f32x4;
typedef __attribute__((ext_vector_type(8))) short short8;
typedef __attribute__((ext_vector_type(4))) short short4v;
typedef __attribute__((ext_vector_type(2))) short short2v;

__device__ __forceinline__ short f2bf(float f) {
  __hip_bfloat16 h = __float2bfloat16(f);
  return *reinterpret_cast<short*>(&h);
}

__device__ __forceinline__ float b2f(short s) {
  union { unsigned u; float f; } v;
  v.u = ((unsigned)(unsigned short)s) << 16;
  return v.f;
}

// XOR-swizzled byte offset within a [rows][128B] LDS tile (R4-verified mapping)
__device__ __forceinline__ int swz(int row, int bc) { return (row << 7) + (bc ^ ((row & 7) << 4)); }

// async global->LDS, 16B per lane; LDS dest = wave-uniform base + lane*16
__device__ __forceinline__ void gl_lds16(const short* g, short* l) {
  __builtin_amdgcn_global_load_lds((const __attribute__((address_space(1))) void*)g,
                                   (__attribute__((address_space(3))) void*)l, 16, 0, 0);
}

// ---- prep: weight transpose+cast (bid<1024) + x/memory fp32->bf16 (bid>=1024) ----
__global__ __launch_bounds__(256) void prep_kernel(const float* __restrict__ x, const float* __restrict__ memory,
                                                   const float* __restrict__ Wq, const float* __restrict__ Wk,
                                                   const float* __restrict__ Wv, const float* __restrict__ Wo,
                                                   short* __restrict__ wt, short* __restrict__ xbf,
                                                   short* __restrict__ membf) {
  __shared__ float tile[64][68];
  const int bid = blockIdx.x;
  const int tid = threadIdx.x;
  if (bid < 1024) {
    const int widx = bid >> 8;
    const int rem = bid & 255;
    const int kt = rem >> 4, nt = rem & 15;
    const float* W = (widx == 0) ? Wq : (widx == 1) ? Wk : (widx == 2) ? Wv : Wo;
    {
      const int r = tid >> 2, c0 = (tid & 3) << 4;
      const float* src = W + (size_t)(kt * 64 + r) * DIM + nt * 64 + c0;
#pragma unroll
      for (int j = 0; j < 4; ++j)
        *reinterpret_cast<f32x4*>(&tile[r][c0 + 4 * j]) = *reinterpret_cast<const f32x4*>(src + 4 * j);
    }
    __syncthreads();
    {
      const int n = tid >> 2, k0 = (tid & 3) << 4;
      short outv[16];
#pragma unroll
      for (int j = 0; j < 16; ++j) outv[j] = f2bf(tile[k0 + j][n]);
      short* dst = wt + (size_t)widx * DIM * DIM + (size_t)(nt * 64 + n) * DIM + kt * 64 + k0;
      *reinterpret_cast<short8*>(dst) = *reinterpret_cast<short8*>(&outv[0]);
      *reinterpret_cast<short8*>(dst + 8) = *reinterpret_cast<short8*>(&outv[8]);
    }
  } else {
    const int cid = bid - 1024;
    const float* src = (cid < 1024) ? x : memory;
    short* dst = (cid < 1024) ? xbf : membf;
    const size_t base = (size_t)(cid & 1023) * 4096 + (size_t)tid * 16;
    const float* s = src + base;
    const f32x4 f0 = *reinterpret_cast<const f32x4*>(s);
    const f32x4 f1 = *reinterpret_cast<const f32x4*>(s + 4);
    const f32x4 f2 = *reinterpret_cast<const f32x4*>(s + 8);
    const f32x4 f3 = *reinterpret_cast<const f32x4*>(s + 12);
    short8 o0, o1;
#pragma unroll
    for (int j = 0; j < 4; ++j) {
      o0[j] = f2bf(f0[j]);
      o0[4 + j] = f2bf(f1[j]);
      o1[j] = f2bf(f2[j]);
      o1[4 + j] = f2bf(f3[j]);
    }
    *reinterpret_cast<short8*>(dst + base) = o0;
    *reinterpret_cast<short8*>(dst + base + 8) = o1;
  }
}

// ---- shared GEMM main loop: C[TM x 128] tile, BK=64, global_load_lds staging,
// LDS chunk-swizzled via pre-swizzled global source (chunk ^= row&7). ----
template <int TM, int MF>
__device__ __forceinline__ void mm_loop(const short* __restrict__ A, const short* __restrict__ Bt, short* a_lds,
                                        short* b_lds, int bm, int bn, int w, int lane, f32x4 (&acc)[MF][4]) {
  const int lm = lane & 15, g = lane >> 4;
  const int wr = w >> 1, wc = w & 1;
  const int lr8 = lane >> 3;                 // row within 8-row wave-write
  const int gch = (lane & 7) ^ (lr8 & 7);    // pre-swizzled source chunk (16B units)
  const short* Aw = A + (size_t)(bm * TM + w * 8 + lr8) * 1024 + gch * 8;
  const short* Bw = Bt + (size_t)(bn * 128 + w * 8 + lr8) * 1024 + gch * 8;
  short* al = a_lds + w * 512;  // wave-uniform LDS bases
  short* bl = b_lds + w * 512;
  const int axor = lm & 7;
  constexpr int JA = TM / 32;

  for (int k0 = 0; k0 < 1024; k0 += 64) {
    __syncthreads();
#pragma unroll
    for (int j = 0; j < JA; ++j) gl_lds16(Aw + (size_t)j * 32 * 1024 + k0, al + j * 2048);
#pragma unroll
    for (int j = 0; j < 4; ++j) gl_lds16(Bw + (size_t)j * 32 * 1024 + k0, bl + j * 2048);
    __syncthreads();  // compiler drains vmcnt before barrier -> tiles ready
    short8 afr[MF][2], bfr[4][2];
#pragma unroll
    for (int mi = 0; mi < MF; ++mi)
#pragma unroll
      for (int kk = 0; kk < 2; ++kk)
        afr[mi][kk] = *reinterpret_cast<const short8*>(
            &a_lds[(wr * (TM / 2) + mi * 16 + lm) * 64 + (((kk << 2) + g) ^ axor) * 8]);
#pragma unroll
    for (int nj = 0; nj < 4; ++nj)
#pragma unroll
      for (int kk = 0; kk < 2; ++kk)
        bfr[nj][kk] = *reinterpret_cast<const short8*>(
            &b_lds[(wc * 64 + nj * 16 + lm) * 64 + (((kk << 2) + g) ^ axor) * 8]);
#pragma unroll
    for (int mi = 0; mi < MF; ++mi)
#pragma unroll
      for (int nj = 0; nj < 4; ++nj)
#pragma unroll
        for (int kk = 0; kk < 2; ++kk)
          acc[mi][nj] = __builtin_amdgcn_mfma_f32_16x16x32_bf16(afr[mi][kk], bfr[nj][kk], acc[mi][nj], 0, 0, 0);
  }
}

// ---- merged Q/K/V projection GEMM: grid 768 (seg = Q/K/V), 128x128 tiles ----
// Q output pre-scaled by 1/sqrt(HD) = 0.125 (folded out of the attention loop).
__global__ __launch_bounds__(256, 3) void qkv_gemm(const short* __restrict__ xbf, const short* __restrict__ membf,
                                                   const short* __restrict__ wt, short* __restrict__ q_ws,
                                                   float* __restrict__ k_out, short* __restrict__ k_bf,
                                                   float* __restrict__ v_out, short* __restrict__ v_bf) {
  __shared__ short a_lds[128 * 64];
  __shared__ short b_lds[128 * 64];
  const int bid = blockIdx.x;
  const int seg = bid >> 8, rem = bid & 255;
  const int bm = rem & 31, bn = rem >> 5;
  const int tid = threadIdx.x, lane = tid & 63, w = tid >> 6;
  const short* A = (seg == 0) ? xbf : membf;
  const short* B = wt + ((size_t)seg << 20);
  f32x4 acc[4][4];
#pragma unroll
  for (int i = 0; i < 4; ++i)
#pragma unroll
    for (int j = 0; j < 4; ++j) acc[i][j] = (f32x4){0.f, 0.f, 0.f, 0.f};
  mm_loop<128, 4>(A, B, a_lds, b_lds, bm, bn, w, lane, acc);

  const int lm = lane & 15, g4 = (lane >> 4) << 2;
  const int wr = w >> 1, wc = w & 1;
#pragma unroll
  for (int mi = 0; mi < 4; ++mi)
#pragma unroll
    for (int nj = 0; nj < 4; ++nj)
#pragma unroll
      for (int r = 0; r < 4; ++r) {
        const int row = bm * 128 + wr * 64 + mi * 16 + g4 + r;
        const int col = bn * 128 + wc * 64 + nj * 16 + lm;
        const float v = acc[mi][nj][r];
        const int b = row >> 11, t = row & 2047, hh = col >> 6, hd = col & 63;
        const size_t idx = (((size_t)b * NH + hh) * LS + t) * HD + hd;
        if (seg == 0) {
          q_ws[idx] = f2bf(v * 0.125f);
        } else if (seg == 1) {
          k_out[idx] = v;
          k_bf[idx] = f2bf(v);
        } else {
          v_out[idx] = v;
          v_bf[idx] = f2bf(v);
        }
      }
}

// ---- output projection GEMM: 64x128 tiles, grid 512 (2 blocks/CU) ----
__global__ __launch_bounds__(256, 3) void o_gemm(const short* __restrict__ attn_bf, const short* __restrict__ wto,
                                                 float* __restrict__ outp) {
  __shared__ short a_lds[64 * 64];
  __shared__ short b_lds[128 * 64];
  const int bid = blockIdx.x;
  const int bm = bid & 63, bn = bid >> 6;
  const int tid = threadIdx.x, lane = tid & 63, w = tid >> 6;
  f32x4 acc[2][4];
#pragma unroll
  for (int i = 0; i < 2; ++i)
#pragma unroll
    for (int j = 0; j < 4; ++j) acc[i][j] = (f32x4){0.f, 0.f, 0.f, 0.f};
  mm_loop<64, 2>(attn_bf, wto, a_lds, b_lds, bm, bn, w, lane, acc);

  const int lm = lane & 15, g4 = (lane >> 4) << 2;
  const int wr = w >> 1, wc = w & 1;
#pragma unroll
  for (int mi = 0; mi < 2; ++mi)
#pragma unroll
    for (int nj = 0; nj < 4; ++nj)
#pragma unroll
      for (int r = 0; r < 4; ++r) {
        const int row = bm * 64 + wr * 32 + mi * 16 + g4 + r;
        const int col = bn * 128 + wc * 64 + nj * 16 + lm;
        outp[(size_t)row * DIM + col] = acc[mi][nj][r];
      }
}

// ---- fused flash attention v10: R3 pipeline + swizzled LDS (25088 B, 6 blk/CU)
// + split-s (flash-decoding): grid 2048, each block does half the s-range and
// writes normalized partial O (bf16) + LSE; combine_kernel merges. ----
__global__ __launch_bounds__(256, 6) void attn_kernel(const short* __restrict__ qw, const short* __restrict__ kbf,
                                                      const short* __restrict__ vbf, const float* __restrict__ pe,
                                                      const float* __restrict__ mask, short* __restrict__ pO,
                                                      float* __restrict__ lse_ws) {
  __shared__ __align__(16) char k_raw[8192];   // K tile [s=64][d=64], swizzled
  __shared__ __align__(16) char vt_raw[8192];  // V^T tile [d=64][s=64], swizzled
  __shared__ __align__(16) char p_raw[8192];   // P per wave [t=16][s=64], swizzled
  __shared__ float sc_lds[4][16];
  __shared__ float l_lds[4][16];
  const int bid = blockIdx.x;
  const int b = bid & 1;
  const int qt = (bid >> 1) & 31;
  const int h = (bid >> 6) & 15;
  const int sh = bid >> 10;  // s-half
  const int bh = b * NH + h;
  const int tid = threadIdx.x, lane = tid & 63, w = tid >> 6;
  const int qbase = qt * 64 + w * 16;
  const int lm = lane & 15, g = lane >> 4, g8 = g << 3, g16 = g << 4, g4 = g << 2;
  constexpr float L2E = 1.4426950408889634f;

  // Q fragment (B-operand of swapped QK, pre-scaled by 0.125): lane lm <-> q-row qbase+lm
  short8 qfr[2];
#pragma unroll
  for (int kk = 0; kk < 2; ++kk)
    qfr[kk] = *reinterpret_cast<const short8*>(qw + ((size_t)bh * LT + qbase + lm) * HD + kk * 32 + g8);

  float m_run = -1e30f, l_run = 0.f;
  f32x4 acc_o[4];
#pragma unroll
  for (int dj = 0; dj < 4; ++dj) acc_o[dj] = (f32x4){0.f, 0.f, 0.f, 0.f};

  const int t_lane = qbase + lm;
  const float* pe_row = pe + (size_t)h * LT * LS + (size_t)t_lane * LS;
  const float* mask_row = mask + (size_t)t_lane * LS;

  const int srow = tid >> 2, scol0 = (tid & 3) << 4;  // K staging: 4 lanes per row
  const int kb = scol0 * 2;                           // K staging byte col
  const int vs2 = (lane & 31) << 1;                   // V staging rows
  const int vd0 = (w << 4) + ((lane >> 5) << 3);      // V staging d-slab

  const int s_beg = sh * (LS / 2), s_end = s_beg + (LS / 2);

  for (int s0 = s_beg; s0 < s_end; s0 += 64) {
    // stage K tile [64 s][64 d] and V^T tile [64 d][64 s], swizzled
    {
      const short* ksrc = kbf + ((size_t)bh * LS + s0 + srow) * HD + scol0;
      *reinterpret_cast<short8*>(k_raw + swz(srow, kb)) = *reinterpret_cast<const short8*>(ksrc);
      *reinterpret_cast<short8*>(k_raw + swz(srow, kb + 16)) = *reinterpret_cast<const short8*>(ksrc + 8);
      const short* vsrc = vbf + ((size_t)bh * LS + s0 + vs2) * HD + vd0;
      const short8 va = *reinterpret_cast<const short8*>(vsrc);
      const short8 vb = *reinterpret_cast<const short8*>(vsrc + HD);
#pragma unroll
      for (int j = 0; j < 8; ++j) {
        short2v pr = {va[j], vb[j]};
        *reinterpret_cast<short2v*>(vt_raw + swz(vd0 + j, vs2 * 2)) = pr;
      }
    }
    __syncthreads();

    // pe + mask vector loads (coalesced f32x4)
    f32x4 pm[4];
    {
      f32x4 mv[4];
#pragma unroll
      for (int nj = 0; nj < 4; ++nj) {
        const int sb = s0 + nj * 16 + g4;
        pm[nj] = *reinterpret_cast<const f32x4*>(pe_row + sb);
        mv[nj] = *reinterpret_cast<const f32x4*>(mask_row + sb);
      }
#pragma unroll
      for (int nj = 0; nj < 4; ++nj) pm[nj] += mv[nj];
    }

    // S^T = K Q^T : accs[nj][r] = S[s = s0+nj*16+g4+r][t = qbase+lm] (pre-scaled)
    f32x4 accs[4];
#pragma unroll
    for (int nj = 0; nj < 4; ++nj) {
      accs[nj] = (f32x4){0.f, 0.f, 0.f, 0.f};
#pragma unroll
      for (int kk = 0; kk < 2; ++kk) {
        const short8 kfr = *reinterpret_cast<const short8*>(k_raw + swz(nj * 16 + lm, kk * 64 + g16));
        accs[nj] = __builtin_amdgcn_mfma_f32_16x16x32_bf16(kfr, qfr[kk], accs[nj], 0, 0, 0);
      }
    }

#pragma unroll
    for (int nj = 0; nj < 4; ++nj)
#pragma unroll
      for (int r = 0; r < 4; ++r) accs[nj][r] += pm[nj][r];

    float mx = accs[0][0];
#pragma unroll
    for (int nj = 0; nj < 4; ++nj)
#pragma unroll
      for (int r = 0; r < 4; ++r) mx = fmaxf(mx, accs[nj][r]);
    mx = fmaxf(mx, __shfl_xor(mx, 16));
    mx = fmaxf(mx, __shfl_xor(mx, 32));
    const float mnew = fmaxf(m_run, mx);
    const float nm = mnew * L2E;
    float rs = 0.f;
#pragma unroll
    for (int nj = 0; nj < 4; ++nj)
#pragma unroll
      for (int r = 0; r < 4; ++r) {
        const float p = exp2f(fmaf(accs[nj][r], L2E, -nm));
        accs[nj][r] = p;
        rs += p;
      }
    rs += __shfl_xor(rs, 16);
    rs += __shfl_xor(rs, 32);
    const float sc = exp2f(fmaf(m_run, L2E, -nm));
    l_run = l_run * sc + rs;
    m_run = mnew;

    // write P[t][s] (wave-private region; in-order DS ops)
#pragma unroll
    for (int nj = 0; nj < 4; ++nj) {
      short4v pk = {f2bf(accs[nj][0]), f2bf(accs[nj][1]), f2bf(accs[nj][2]), f2bf(accs[nj][3])};
      *reinterpret_cast<short4v*>(p_raw + (w << 11) + swz(lm, nj * 32 + g * 8)) = pk;
    }
    if (g == 0) sc_lds[w][lm] = sc;
    const f32x4 sc4 = *reinterpret_cast<const f32x4*>(&sc_lds[w][g4]);
#pragma unroll
    for (int dj = 0; dj < 4; ++dj)
#pragma unroll
      for (int r = 0; r < 4; ++r) acc_o[dj][r] *= sc4[r];

    // O += P V
#pragma unroll
    for (int kk = 0; kk < 2; ++kk) {
      const short8 pfr = *reinterpret_cast<const short8*>(p_raw + (w << 11) + swz(lm, kk * 64 + g16));
#pragma unroll
      for (int dj = 0; dj < 4; ++dj) {
        const short8 vfr = *reinterpret_cast<const short8*>(vt_raw + swz(dj * 16 + lm, kk * 64 + g16));
        acc_o[dj] = __builtin_amdgcn_mfma_f32_16x16x32_bf16(pfr, vfr, acc_o[dj], 0, 0, 0);
      }
    }
    __syncthreads();  // protect k_raw/vt_raw before next stage
  }

  // epilogue: write normalized partial O (bf16) + LSE (log2 units)
  if (g == 0) l_lds[w][lm] = l_run;
  if (g == 0) lse_ws[((size_t)(sh * NB + b) * NH + h) * LT + t_lane] = fmaf(m_run, L2E, __log2f(l_run));
  const f32x4 l4 = *reinterpret_cast<const f32x4*>(&l_lds[w][g4]);
#pragma unroll
  for (int r = 0; r < 4; ++r) {
    const float inv = 1.f / l4[r];
    const int t = qbase + g4 + r;
    const size_t prow = ((size_t)(sh * NB + b) * NH + h) * LT + t;
#pragma unroll
    for (int dj = 0; dj < 4; ++dj) {
      const int d = dj * 16 + lm;
      pO[prow * HD + d] = f2bf(acc_o[dj][r] * inv);
    }
  }
}

// ---- combine: merge the two s-half partials -> attn_ws [B, LT, H*HD] bf16 ----
__global__ __launch_bounds__(256) void combine_kernel(const short* __restrict__ pO,
                                                      const float* __restrict__ lse,
                                                      short* __restrict__ aout) {
  const int gid = blockIdx.x * 256 + threadIdx.x;  // 524288 threads
  const int row = gid >> 3;                        // (b*NH+h)*LT + t, 65536 rows
  const int d0 = (gid & 7) << 3;
  const int b = row >> 15;
  const int h = (row >> 11) & 15;
  const int t = row & 2047;
  const size_t r0 = (size_t)row;
  const size_t r1 = (size_t)row + (size_t)NB * NH * LT;
  const float l0 = lse[r0], l1 = lse[r1];
  const float mm = fmaxf(l0, l1);
  float w0 = exp2f(l0 - mm), w1 = exp2f(l1 - mm);
  const float inv = 1.f / (w0 + w1);
  w0 *= inv;
  w1 *= inv;
  const short8 o0 = *reinterpret_cast<const short8*>(pO + r0 * HD + d0);
  const short8 o1 = *reinterpret_cast<const short8*>(pO + r1 * HD + d0);
  short8 out;
#pragma unroll
  for (int j = 0; j < 8; ++j) out[j] = f2bf(b2f(o0[j]) * w0 + b2f(o1[j]) * w1);
  *reinterpret_cast<short8*>(aout + ((size_t)b * LT + t) * DIM + h * HD + d0) = out;
}

extern "C" void kernel_launch(void* const* d_in, const int* in_sizes, int n_in, void* d_out, int out_size,
                              void* d_ws, size_t ws_size, hipStream_t stream) {
  (void)in_sizes;
  (void)n_in;
  (void)out_size;
  (void)ws_size;
  const float* x = (const float*)d_in[0];
  const float* memory = (const float*)d_in[1];
  const float* pe = (const float*)d_in[2];
  const float* mask = (const float*)d_in[3];
  const float* Wq = (const float*)d_in[4];
  const float* Wk = (const float*)d_in[5];
  const float* Wv = (const float*)d_in[6];
  const float* Wo = (const float*)d_in[7];
  float* outp = (float*)d_out;
  float* k_out = outp + (size_t)NB * NH * LS * HD;
  float* v_out = k_out + (size_t)NB * NH * LS * HD;
  char* ws = (char*)d_ws;
  short* q_ws = (short*)ws;                      //  8 MiB: Q bf16 [B,H,LT,HD] (pre-scaled by 0.125)
  short* attn_ws = (short*)(ws + (8u << 20));    //  8 MiB: attn out bf16 [B,LT,D]
  short* wt = (short*)(ws + (16u << 20));        //  8 MiB: 4x Wt bf16 [N][K]; first 6 MiB dead post-qkv
  short* k_bf = (short*)(ws + (24u << 20));      //  8 MiB: K bf16 [B,H,LS,HD]
  short* v_bf = (short*)(ws + (32u << 20));      //  8 MiB: V bf16 [B,H,LS,HD]
  short* xbf = (short*)(ws + (40u << 20));       //  8 MiB: x bf16 (dead post-qkv)
  short* membf = (short*)(ws + (48u << 20));     //  8 MiB: memory bf16 (dead post-qkv)
  // attn-phase reuse of dead regions:
  short* pO = xbf;                                  // 16 MiB: partial O bf16 [half][B][H][LT][HD]
  float* lse_ws = (float*)(ws + (16u << 20) + (6u << 20));  // 0.5 MiB in wt hole? NO - wt[3] lives at 22-24 MiB.
  lse_ws = (float*)(ws + (16u << 20));              // 0.5 MiB: LSE fp32 [half][B][H][LT] (wt[0] region, dead)

  prep_kernel<<<dim3(3072), dim3(256), 0, stream>>>(x, memory, Wq, Wk, Wv, Wo, wt, xbf, membf);
  qkv_gemm<<<dim3(768), dim3(256), 0, stream>>>(xbf, membf, wt, q_ws, k_out, k_bf, v_out, v_bf);
  attn_kernel<<<dim3(2048), dim3(256), 0, stream>>>(q_ws, k_bf, v_bf, pe, mask, pO, lse_ws);
  combine_kernel<<<dim3(2048), dim3(256), 0, stream>>>(pO, lse_ws, attn_ws);
  o_gemm<<<dim3(512), dim3(256), 0, stream>>>(attn_ws, wt + (3u << 20), outp);
}

// Round 11
// 276.097 us; speedup vs baseline: 1.3696x; 1.3696x over previous
//
#include <hip/hip_runtime.h>
#include <hip/hip_bf16.h>
#include <stdint.h>

#define NB 2
#define NH 16
#define LT 2048
#define LS 2048
#define DIM 1024
#define HD 64

typedef __attribute__((ext_vector_type(4))) float f32x4;
typedef __attribute__((ext_vector_type(8))) short short8;
typedef __attribute__((ext_vector_type(4))) short short4v;
typedef __attribute__((ext_vector_type(2))) short short2v;

__device__ __forceinline__ short f2bf(float f) {
  __hip_bfloat16 h = __float2bfloat16(f);
  return *reinterpret_cast<short*>(&h);
}

__device__ __forceinline__ float b2f(short s) {
  union { unsigned u; float f; } v;
  v.u = ((unsigned)(unsigned short)s) << 16;
  return v.f;
}

// XOR-swizzled byte offset within a [rows][128B] LDS tile (R4/R10-verified mapping)
__device__ __forceinline__ int swz(int row, int bc) { return (row << 7) + (bc ^ ((row & 7) << 4)); }

// async global->LDS, 16B per lane; LDS dest = wave-uniform base + lane*16
__device__ __forceinline__ void gl_lds16(const short* g, short* l) {
  __builtin_amdgcn_global_load_lds((const __attribute__((address_space(1))) void*)g,
                                   (__attribute__((address_space(3))) void*)l, 16, 0, 0);
}

// ---- prep: weight transpose+cast (bid<1024) + x/memory fp32->bf16 (bid>=1024) ----
__global__ __launch_bounds__(256) void prep_kernel(const float* __restrict__ x, const float* __restrict__ memory,
                                                   const float* __restrict__ Wq, const float* __restrict__ Wk,
                                                   const float* __restrict__ Wv, const float* __restrict__ Wo,
                                                   short* __restrict__ wt, short* __restrict__ xbf,
                                                   short* __restrict__ membf) {
  __shared__ float tile[64][68];
  const int bid = blockIdx.x;
  const int tid = threadIdx.x;
  if (bid < 1024) {
    const int widx = bid >> 8;
    const int rem = bid & 255;
    const int kt = rem >> 4, nt = rem & 15;
    const float* W = (widx == 0) ? Wq : (widx == 1) ? Wk : (widx == 2) ? Wv : Wo;
    {
      const int r = tid >> 2, c0 = (tid & 3) << 4;
      const float* src = W + (size_t)(kt * 64 + r) * DIM + nt * 64 + c0;
#pragma unroll
      for (int j = 0; j < 4; ++j)
        *reinterpret_cast<f32x4*>(&tile[r][c0 + 4 * j]) = *reinterpret_cast<const f32x4*>(src + 4 * j);
    }
    __syncthreads();
    {
      const int n = tid >> 2, k0 = (tid & 3) << 4;
      short outv[16];
#pragma unroll
      for (int j = 0; j < 16; ++j) outv[j] = f2bf(tile[k0 + j][n]);
      short* dst = wt + (size_t)widx * DIM * DIM + (size_t)(nt * 64 + n) * DIM + kt * 64 + k0;
      *reinterpret_cast<short8*>(dst) = *reinterpret_cast<short8*>(&outv[0]);
      *reinterpret_cast<short8*>(dst + 8) = *reinterpret_cast<short8*>(&outv[8]);
    }
  } else {
    const int cid = bid - 1024;
    const float* src = (cid < 1024) ? x : memory;
    short* dst = (cid < 1024) ? xbf : membf;
    const size_t base = (size_t)(cid & 1023) * 4096 + (size_t)tid * 16;
    const float* s = src + base;
    const f32x4 f0 = *reinterpret_cast<const f32x4*>(s);
    const f32x4 f1 = *reinterpret_cast<const f32x4*>(s + 4);
    const f32x4 f2 = *reinterpret_cast<const f32x4*>(s + 8);
    const f32x4 f3 = *reinterpret_cast<const f32x4*>(s + 12);
    short8 o0, o1;
#pragma unroll
    for (int j = 0; j < 4; ++j) {
      o0[j] = f2bf(f0[j]);
      o0[4 + j] = f2bf(f1[j]);
      o1[j] = f2bf(f2[j]);
      o1[4 + j] = f2bf(f3[j]);
    }
    *reinterpret_cast<short8*>(dst + base) = o0;
    *reinterpret_cast<short8*>(dst + base + 8) = o1;
  }
}

// ---- pm fusion: pm[h][t][s] = bf16(pe[h][t][s] + mask[t][s]) ----
// grid 2048 (one t-row per block), 256 threads x 8 s-elems; mask row read once.
__global__ __launch_bounds__(256) void pm_kernel(const float* __restrict__ pe, const float* __restrict__ mask,
                                                 short* __restrict__ pmb) {
  const int t = blockIdx.x;
  const int s0 = threadIdx.x << 3;
  const f32x4 m0 = *reinterpret_cast<const f32x4*>(mask + (size_t)t * LS + s0);
  const f32x4 m1 = *reinterpret_cast<const f32x4*>(mask + (size_t)t * LS + s0 + 4);
#pragma unroll 4
  for (int h = 0; h < NH; ++h) {
    const float* per = pe + ((size_t)h * LT + t) * LS + s0;
    const f32x4 p0 = *reinterpret_cast<const f32x4*>(per);
    const f32x4 p1 = *reinterpret_cast<const f32x4*>(per + 4);
    short8 o;
#pragma unroll
    for (int j = 0; j < 4; ++j) {
      o[j] = f2bf(p0[j] + m0[j]);
      o[4 + j] = f2bf(p1[j] + m1[j]);
    }
    *reinterpret_cast<short8*>(pmb + ((size_t)h * LT + t) * LS + s0) = o;
  }
}

// ---- shared GEMM main loop: C[TM x 128] tile, BK=64, global_load_lds staging,
// LDS chunk-swizzled via pre-swizzled global source (chunk ^= row&7). ----
template <int TM, int MF>
__device__ __forceinline__ void mm_loop(const short* __restrict__ A, const short* __restrict__ Bt, short* a_lds,
                                        short* b_lds, int bm, int bn, int w, int lane, f32x4 (&acc)[MF][4]) {
  const int lm = lane & 15, g = lane >> 4;
  const int wr = w >> 1, wc = w & 1;
  const int lr8 = lane >> 3;                 // row within 8-row wave-write
  const int gch = (lane & 7) ^ (lr8 & 7);    // pre-swizzled source chunk (16B units)
  const short* Aw = A + (size_t)(bm * TM + w * 8 + lr8) * 1024 + gch * 8;
  const short* Bw = Bt + (size_t)(bn * 128 + w * 8 + lr8) * 1024 + gch * 8;
  short* al = a_lds + w * 512;  // wave-uniform LDS bases
  short* bl = b_lds + w * 512;
  const int axor = lm & 7;
  constexpr int JA = TM / 32;

  for (int k0 = 0; k0 < 1024; k0 += 64) {
    __syncthreads();
#pragma unroll
    for (int j = 0; j < JA; ++j) gl_lds16(Aw + (size_t)j * 32 * 1024 + k0, al + j * 2048);
#pragma unroll
    for (int j = 0; j < 4; ++j) gl_lds16(Bw + (size_t)j * 32 * 1024 + k0, bl + j * 2048);
    __syncthreads();  // compiler drains vmcnt before barrier -> tiles ready
    short8 afr[MF][2], bfr[4][2];
#pragma unroll
    for (int mi = 0; mi < MF; ++mi)
#pragma unroll
      for (int kk = 0; kk < 2; ++kk)
        afr[mi][kk] = *reinterpret_cast<const short8*>(
            &a_lds[(wr * (TM / 2) + mi * 16 + lm) * 64 + (((kk << 2) + g) ^ axor) * 8]);
#pragma unroll
    for (int nj = 0; nj < 4; ++nj)
#pragma unroll
      for (int kk = 0; kk < 2; ++kk)
        bfr[nj][kk] = *reinterpret_cast<const short8*>(
            &b_lds[(wc * 64 + nj * 16 + lm) * 64 + (((kk << 2) + g) ^ axor) * 8]);
#pragma unroll
    for (int mi = 0; mi < MF; ++mi)
#pragma unroll
      for (int nj = 0; nj < 4; ++nj)
#pragma unroll
        for (int kk = 0; kk < 2; ++kk)
          acc[mi][nj] = __builtin_amdgcn_mfma_f32_16x16x32_bf16(afr[mi][kk], bfr[nj][kk], acc[mi][nj], 0, 0, 0);
  }
}

// ---- merged Q/K/V projection GEMM: grid 768 (seg = Q/K/V), 128x128 tiles ----
// Q output pre-scaled by 1/sqrt(HD) = 0.125 (folded out of the attention loop).
__global__ __launch_bounds__(256, 3) void qkv_gemm(const short* __restrict__ xbf, const short* __restrict__ membf,
                                                   const short* __restrict__ wt, short* __restrict__ q_ws,
                                                   float* __restrict__ k_out, short* __restrict__ k_bf,
                                                   float* __restrict__ v_out, short* __restrict__ v_bf) {
  __shared__ short a_lds[128 * 64];
  __shared__ short b_lds[128 * 64];
  const int bid = blockIdx.x;
  const int seg = bid >> 8, rem = bid & 255;
  const int bm = rem & 31, bn = rem >> 5;
  const int tid = threadIdx.x, lane = tid & 63, w = tid >> 6;
  const short* A = (seg == 0) ? xbf : membf;
  const short* B = wt + ((size_t)seg << 20);
  f32x4 acc[4][4];
#pragma unroll
  for (int i = 0; i < 4; ++i)
#pragma unroll
    for (int j = 0; j < 4; ++j) acc[i][j] = (f32x4){0.f, 0.f, 0.f, 0.f};
  mm_loop<128, 4>(A, B, a_lds, b_lds, bm, bn, w, lane, acc);

  const int lm = lane & 15, g4 = (lane >> 4) << 2;
  const int wr = w >> 1, wc = w & 1;
#pragma unroll
  for (int mi = 0; mi < 4; ++mi)
#pragma unroll
    for (int nj = 0; nj < 4; ++nj)
#pragma unroll
      for (int r = 0; r < 4; ++r) {
        const int row = bm * 128 + wr * 64 + mi * 16 + g4 + r;
        const int col = bn * 128 + wc * 64 + nj * 16 + lm;
        const float v = acc[mi][nj][r];
        const int b = row >> 11, t = row & 2047, hh = col >> 6, hd = col & 63;
        const size_t idx = (((size_t)b * NH + hh) * LS + t) * HD + hd;
        if (seg == 0) {
          q_ws[idx] = f2bf(v * 0.125f);
        } else if (seg == 1) {
          k_out[idx] = v;
          k_bf[idx] = f2bf(v);
        } else {
          v_out[idx] = v;
          v_bf[idx] = f2bf(v);
        }
      }
}

// ---- output projection GEMM: 64x128 tiles, grid 512 (2 blocks/CU) ----
__global__ __launch_bounds__(256, 3) void o_gemm(const short* __restrict__ attn_bf, const short* __restrict__ wto,
                                                 float* __restrict__ outp) {
  __shared__ short a_lds[64 * 64];
  __shared__ short b_lds[128 * 64];
  const int bid = blockIdx.x;
  const int bm = bid & 63, bn = bid >> 6;
  const int tid = threadIdx.x, lane = tid & 63, w = tid >> 6;
  f32x4 acc[2][4];
#pragma unroll
  for (int i = 0; i < 2; ++i)
#pragma unroll
    for (int j = 0; j < 4; ++j) acc[i][j] = (f32x4){0.f, 0.f, 0.f, 0.f};
  mm_loop<64, 2>(attn_bf, wto, a_lds, b_lds, bm, bn, w, lane, acc);

  const int lm = lane & 15, g4 = (lane >> 4) << 2;
  const int wr = w >> 1, wc = w & 1;
#pragma unroll
  for (int mi = 0; mi < 2; ++mi)
#pragma unroll
    for (int nj = 0; nj < 4; ++nj)
#pragma unroll
      for (int r = 0; r < 4; ++r) {
        const int row = bm * 64 + wr * 32 + mi * 16 + g4 + r;
        const int col = bn * 128 + wc * 64 + nj * 16 + lm;
        outp[(size_t)row * DIM + col] = acc[mi][nj][r];
      }
}

// ---- fused flash attention v11: R3 pipeline + swizzled LDS; PM=1 reads fused
// bf16 pe+mask (4x fewer bytes, L3-resident), PM=0 falls back to fp32 pe+mask. ----
// 1 block = 64 q-rows of one (b,h); 4 waves, 16 q-rows each. grid = 1024.
template <int PM>
__global__ __launch_bounds__(256, 4) void attn_kernel(const short* __restrict__ qw, const short* __restrict__ kbf,
                                                      const short* __restrict__ vbf, const float* __restrict__ pe,
                                                      const float* __restrict__ mask,
                                                      const short* __restrict__ pmb, short* __restrict__ aout) {
  __shared__ __align__(16) char k_raw[8192];   // K tile [s=64][d=64], swizzled
  __shared__ __align__(16) char vt_raw[8192];  // V^T tile [d=64][s=64], swizzled
  __shared__ __align__(16) char p_raw[8192];   // P per wave [t=16][s=64], swizzled
  __shared__ float sc_lds[4][16];
  __shared__ float l_lds[4][16];
  const int bid = blockIdx.x;
  const int b = bid & 1;
  const int qt = (bid >> 1) & 31;
  const int h = (bid >> 6) & 15;
  const int bh = b * NH + h;
  const int tid = threadIdx.x, lane = tid & 63, w = tid >> 6;
  const int qbase = qt * 64 + w * 16;
  const int lm = lane & 15, g = lane >> 4, g8 = g << 3, g16 = g << 4, g4 = g << 2;
  constexpr float L2E = 1.4426950408889634f;

  // Q fragment (B-operand of swapped QK, pre-scaled by 0.125): lane lm <-> q-row qbase+lm
  short8 qfr[2];
#pragma unroll
  for (int kk = 0; kk < 2; ++kk)
    qfr[kk] = *reinterpret_cast<const short8*>(qw + ((size_t)bh * LT + qbase + lm) * HD + kk * 32 + g8);

  float m_run = -1e30f, l_run = 0.f;
  f32x4 acc_o[4];
#pragma unroll
  for (int dj = 0; dj < 4; ++dj) acc_o[dj] = (f32x4){0.f, 0.f, 0.f, 0.f};

  const int t_lane = qbase + lm;
  const float* pe_row = pe + (size_t)h * LT * LS + (size_t)t_lane * LS;
  const float* mask_row = mask + (size_t)t_lane * LS;
  const short* pm_row = pmb + ((size_t)h * LT + t_lane) * LS;

  const int srow = tid >> 2, scol0 = (tid & 3) << 4;  // K staging: 4 lanes per row
  const int kb = scol0 * 2;                           // K staging byte col
  const int vs2 = (lane & 31) << 1;                   // V staging rows
  const int vd0 = (w << 4) + ((lane >> 5) << 3);      // V staging d-slab

  for (int s0 = 0; s0 < LS; s0 += 64) {
    // stage K tile [64 s][64 d] and V^T tile [64 d][64 s], swizzled
    {
      const short* ksrc = kbf + ((size_t)bh * LS + s0 + srow) * HD + scol0;
      *reinterpret_cast<short8*>(k_raw + swz(srow, kb)) = *reinterpret_cast<const short8*>(ksrc);
      *reinterpret_cast<short8*>(k_raw + swz(srow, kb + 16)) = *reinterpret_cast<const short8*>(ksrc + 8);
      const short* vsrc = vbf + ((size_t)bh * LS + s0 + vs2) * HD + vd0;
      const short8 va = *reinterpret_cast<const short8*>(vsrc);
      const short8 vb = *reinterpret_cast<const short8*>(vsrc + HD);
#pragma unroll
      for (int j = 0; j < 8; ++j) {
        short2v pr = {va[j], vb[j]};
        *reinterpret_cast<short2v*>(vt_raw + swz(vd0 + j, vs2 * 2)) = pr;
      }
    }
    __syncthreads();

    // bias loads: PM=1 -> one bf16 short4 per nj (8B); PM=0 -> fp32 pe+mask f32x4 pairs
    f32x4 pm4[4];
    if (PM) {
#pragma unroll
      for (int nj = 0; nj < 4; ++nj) {
        const short4v pv = *reinterpret_cast<const short4v*>(pm_row + s0 + nj * 16 + g4);
#pragma unroll
        for (int r = 0; r < 4; ++r) pm4[nj][r] = b2f(pv[r]);
      }
    } else {
      f32x4 mv[4];
#pragma unroll
      for (int nj = 0; nj < 4; ++nj) {
        const int sb = s0 + nj * 16 + g4;
        pm4[nj] = *reinterpret_cast<const f32x4*>(pe_row + sb);
        mv[nj] = *reinterpret_cast<const f32x4*>(mask_row + sb);
      }
#pragma unroll
      for (int nj = 0; nj < 4; ++nj) pm4[nj] += mv[nj];
    }

    // S^T = K Q^T : accs[nj][r] = S[s = s0+nj*16+g4+r][t = qbase+lm] (pre-scaled)
    f32x4 accs[4];
#pragma unroll
    for (int nj = 0; nj < 4; ++nj) {
      accs[nj] = (f32x4){0.f, 0.f, 0.f, 0.f};
#pragma unroll
      for (int kk = 0; kk < 2; ++kk) {
        const short8 kfr = *reinterpret_cast<const short8*>(k_raw + swz(nj * 16 + lm, kk * 64 + g16));
        accs[nj] = __builtin_amdgcn_mfma_f32_16x16x32_bf16(kfr, qfr[kk], accs[nj], 0, 0, 0);
      }
    }

#pragma unroll
    for (int nj = 0; nj < 4; ++nj)
#pragma unroll
      for (int r = 0; r < 4; ++r) accs[nj][r] += pm4[nj][r];

    float mx = accs[0][0];
#pragma unroll
    for (int nj = 0; nj < 4; ++nj)
#pragma unroll
      for (int r = 0; r < 4; ++r) mx = fmaxf(mx, accs[nj][r]);
    mx = fmaxf(mx, __shfl_xor(mx, 16));
    mx = fmaxf(mx, __shfl_xor(mx, 32));
    const float mnew = fmaxf(m_run, mx);
    const float nm = mnew * L2E;
    float rs = 0.f;
#pragma unroll
    for (int nj = 0; nj < 4; ++nj)
#pragma unroll
      for (int r = 0; r < 4; ++r) {
        const float p = exp2f(fmaf(accs[nj][r], L2E, -nm));
        accs[nj][r] = p;
        rs += p;
      }
    rs += __shfl_xor(rs, 16);
    rs += __shfl_xor(rs, 32);
    const float sc = exp2f(fmaf(m_run, L2E, -nm));
    l_run = l_run * sc + rs;
    m_run = mnew;

    // write P[t][s] (wave-private region; in-order DS ops)
#pragma unroll
    for (int nj = 0; nj < 4; ++nj) {
      short4v pk = {f2bf(accs[nj][0]), f2bf(accs[nj][1]), f2bf(accs[nj][2]), f2bf(accs[nj][3])};
      *reinterpret_cast<short4v*>(p_raw + (w << 11) + swz(lm, nj * 32 + g * 8)) = pk;
    }
    if (g == 0) sc_lds[w][lm] = sc;
    const f32x4 sc4 = *reinterpret_cast<const f32x4*>(&sc_lds[w][g4]);
#pragma unroll
    for (int dj = 0; dj < 4; ++dj)
#pragma unroll
      for (int r = 0; r < 4; ++r) acc_o[dj][r] *= sc4[r];

    // O += P V
#pragma unroll
    for (int kk = 0; kk < 2; ++kk) {
      const short8 pfr = *reinterpret_cast<const short8*>(p_raw + (w << 11) + swz(lm, kk * 64 + g16));
#pragma unroll
      for (int dj = 0; dj < 4; ++dj) {
        const short8 vfr = *reinterpret_cast<const short8*>(vt_raw + swz(dj * 16 + lm, kk * 64 + g16));
        acc_o[dj] = __builtin_amdgcn_mfma_f32_16x16x32_bf16(pfr, vfr, acc_o[dj], 0, 0, 0);
      }
    }
    __syncthreads();  // protect k_raw/vt_raw before next stage
  }

  // epilogue: redistribute 1/l, write bf16 score_cat layout [B, LT, H*HD]
  if (g == 0) l_lds[w][lm] = l_run;
  const f32x4 l4 = *reinterpret_cast<const f32x4*>(&l_lds[w][g4]);
#pragma unroll
  for (int r = 0; r < 4; ++r) {
    const float inv = 1.f / l4[r];
    const int t = qbase + g4 + r;
#pragma unroll
    for (int dj = 0; dj < 4; ++dj) {
      const int d = dj * 16 + lm;
      aout[((size_t)b * LT + t) * DIM + h * HD + d] = f2bf(acc_o[dj][r] * inv);
    }
  }
}

extern "C" void kernel_launch(void* const* d_in, const int* in_sizes, int n_in, void* d_out, int out_size,
                              void* d_ws, size_t ws_size, hipStream_t stream) {
  (void)in_sizes;
  (void)n_in;
  (void)out_size;
  const float* x = (const float*)d_in[0];
  const float* memory = (const float*)d_in[1];
  const float* pe = (const float*)d_in[2];
  const float* mask = (const float*)d_in[3];
  const float* Wq = (const float*)d_in[4];
  const float* Wk = (const float*)d_in[5];
  const float* Wv = (const float*)d_in[6];
  const float* Wo = (const float*)d_in[7];
  float* outp = (float*)d_out;
  float* k_out = outp + (size_t)NB * NH * LS * HD;
  float* v_out = k_out + (size_t)NB * NH * LS * HD;
  char* ws = (char*)d_ws;
  short* q_ws = (short*)ws;                      //  8 MiB: Q bf16 [B,H,LT,HD] (pre-scaled by 0.125)
  short* attn_ws = (short*)(ws + (8u << 20));    //  8 MiB: attn out bf16 [B,LT,D]
  short* wt = (short*)(ws + (16u << 20));        //  8 MiB: 4x Wt bf16 [N][K]
  short* k_bf = (short*)(ws + (24u << 20));      //  8 MiB: K bf16 [B,H,LS,HD]
  short* v_bf = (short*)(ws + (32u << 20));      //  8 MiB: V bf16 [B,H,LS,HD]
  short* xbf = (short*)(ws + (40u << 20));       //  8 MiB: x bf16 [B*LT, D]
  short* membf = (short*)(ws + (48u << 20));     //  8 MiB: memory bf16 [B*LS, D]
  short* pmb = (short*)(ws + (56ull << 20));     // 128 MiB: pm bf16 [H][LT][LS] (if ws allows)
  const bool use_pm = ws_size >= (184ull << 20);

  prep_kernel<<<dim3(3072), dim3(256), 0, stream>>>(x, memory, Wq, Wk, Wv, Wo, wt, xbf, membf);
  qkv_gemm<<<dim3(768), dim3(256), 0, stream>>>(xbf, membf, wt, q_ws, k_out, k_bf, v_out, v_bf);
  if (use_pm) {
    pm_kernel<<<dim3(2048), dim3(256), 0, stream>>>(pe, mask, pmb);
    attn_kernel<1><<<dim3(1024), dim3(256), 0, stream>>>(q_ws, k_bf, v_bf, pe, mask, pmb, attn_ws);
  } else {
    attn_kernel<0><<<dim3(1024), dim3(256), 0, stream>>>(q_ws, k_bf, v_bf, pe, mask, pmb, attn_ws);
  }
  o_gemm<<<dim3(512), dim3(256), 0, stream>>>(attn_ws, wt + (3u << 20), outp);
}

// Round 12
// 266.622 us; speedup vs baseline: 1.4183x; 1.0355x over previous
//
#include <hip/hip_runtime.h>
#include <hip/hip_bf16.h>
#include <stdint.h>

#define NB 2
#define NH 16
#define LT 2048
#define LS 2048
#define DIM 1024
#define HD 64

typedef __attribute__((ext_vector_type(4))) float f32x4;
typedef __attribute__((ext_vector_type(8))) short short8;
typedef __attribute__((ext_vector_type(4))) short short4v;
typedef __attribute__((ext_vector_type(2))) short short2v;

__device__ __forceinline__ short f2bf(float f) {
  __hip_bfloat16 h = __float2bfloat16(f);
  return *reinterpret_cast<short*>(&h);
}

__device__ __forceinline__ float b2f(short s) {
  union { unsigned u; float f; } v;
  v.u = ((unsigned)(unsigned short)s) << 16;
  return v.f;
}

// XOR-swizzled byte offset within a [rows][128B] LDS tile (R4/R10-verified mapping)
__device__ __forceinline__ int swz(int row, int bc) { return (row << 7) + (bc ^ ((row & 7) << 4)); }

// async global->LDS, 16B per lane; LDS dest = wave-uniform base + lane*16
__device__ __forceinline__ void gl_lds16(const short* g, short* l) {
  __builtin_amdgcn_global_load_lds((const __attribute__((address_space(1))) void*)g,
                                   (__attribute__((address_space(3))) void*)l, 16, 0, 0);
}

// ---- prep: weight transpose+cast (bid<1024) + x/memory fp32->bf16 (bid>=1024) ----
__global__ __launch_bounds__(256) void prep_kernel(const float* __restrict__ x, const float* __restrict__ memory,
                                                   const float* __restrict__ Wq, const float* __restrict__ Wk,
                                                   const float* __restrict__ Wv, const float* __restrict__ Wo,
                                                   short* __restrict__ wt, short* __restrict__ xbf,
                                                   short* __restrict__ membf) {
  __shared__ float tile[64][68];
  const int bid = blockIdx.x;
  const int tid = threadIdx.x;
  if (bid < 1024) {
    const int widx = bid >> 8;
    const int rem = bid & 255;
    const int kt = rem >> 4, nt = rem & 15;
    const float* W = (widx == 0) ? Wq : (widx == 1) ? Wk : (widx == 2) ? Wv : Wo;
    {
      const int r = tid >> 2, c0 = (tid & 3) << 4;
      const float* src = W + (size_t)(kt * 64 + r) * DIM + nt * 64 + c0;
#pragma unroll
      for (int j = 0; j < 4; ++j)
        *reinterpret_cast<f32x4*>(&tile[r][c0 + 4 * j]) = *reinterpret_cast<const f32x4*>(src + 4 * j);
    }
    __syncthreads();
    {
      const int n = tid >> 2, k0 = (tid & 3) << 4;
      short outv[16];
#pragma unroll
      for (int j = 0; j < 16; ++j) outv[j] = f2bf(tile[k0 + j][n]);
      short* dst = wt + (size_t)widx * DIM * DIM + (size_t)(nt * 64 + n) * DIM + kt * 64 + k0;
      *reinterpret_cast<short8*>(dst) = *reinterpret_cast<short8*>(&outv[0]);
      *reinterpret_cast<short8*>(dst + 8) = *reinterpret_cast<short8*>(&outv[8]);
    }
  } else {
    const int cid = bid - 1024;
    const float* src = (cid < 1024) ? x : memory;
    short* dst = (cid < 1024) ? xbf : membf;
    const size_t base = (size_t)(cid & 1023) * 4096 + (size_t)tid * 16;
    const float* s = src + base;
    const f32x4 f0 = *reinterpret_cast<const f32x4*>(s);
    const f32x4 f1 = *reinterpret_cast<const f32x4*>(s + 4);
    const f32x4 f2 = *reinterpret_cast<const f32x4*>(s + 8);
    const f32x4 f3 = *reinterpret_cast<const f32x4*>(s + 12);
    short8 o0, o1;
#pragma unroll
    for (int j = 0; j < 4; ++j) {
      o0[j] = f2bf(f0[j]);
      o0[4 + j] = f2bf(f1[j]);
      o1[j] = f2bf(f2[j]);
      o1[4 + j] = f2bf(f3[j]);
    }
    *reinterpret_cast<short8*>(dst + base) = o0;
    *reinterpret_cast<short8*>(dst + base + 8) = o1;
  }
}

// ---- shared GEMM main loop: C[TM x 128] tile, BK=64, global_load_lds staging,
// LDS chunk-swizzled via pre-swizzled global source (chunk ^= row&7). ----
template <int TM, int MF>
__device__ __forceinline__ void mm_loop(const short* __restrict__ A, const short* __restrict__ Bt, short* a_lds,
                                        short* b_lds, int bm, int bn, int w, int lane, f32x4 (&acc)[MF][4]) {
  const int lm = lane & 15, g = lane >> 4;
  const int wr = w >> 1, wc = w & 1;
  const int lr8 = lane >> 3;                 // row within 8-row wave-write
  const int gch = (lane & 7) ^ (lr8 & 7);    // pre-swizzled source chunk (16B units)
  const short* Aw = A + (size_t)(bm * TM + w * 8 + lr8) * 1024 + gch * 8;
  const short* Bw = Bt + (size_t)(bn * 128 + w * 8 + lr8) * 1024 + gch * 8;
  short* al = a_lds + w * 512;  // wave-uniform LDS bases
  short* bl = b_lds + w * 512;
  const int axor = lm & 7;
  constexpr int JA = TM / 32;

  for (int k0 = 0; k0 < 1024; k0 += 64) {
    __syncthreads();
#pragma unroll
    for (int j = 0; j < JA; ++j) gl_lds16(Aw + (size_t)j * 32 * 1024 + k0, al + j * 2048);
#pragma unroll
    for (int j = 0; j < 4; ++j) gl_lds16(Bw + (size_t)j * 32 * 1024 + k0, bl + j * 2048);
    __syncthreads();  // compiler drains vmcnt before barrier -> tiles ready
    short8 afr[MF][2], bfr[4][2];
#pragma unroll
    for (int mi = 0; mi < MF; ++mi)
#pragma unroll
      for (int kk = 0; kk < 2; ++kk)
        afr[mi][kk] = *reinterpret_cast<const short8*>(
            &a_lds[(wr * (TM / 2) + mi * 16 + lm) * 64 + (((kk << 2) + g) ^ axor) * 8]);
#pragma unroll
    for (int nj = 0; nj < 4; ++nj)
#pragma unroll
      for (int kk = 0; kk < 2; ++kk)
        bfr[nj][kk] = *reinterpret_cast<const short8*>(
            &b_lds[(wc * 64 + nj * 16 + lm) * 64 + (((kk << 2) + g) ^ axor) * 8]);
#pragma unroll
    for (int mi = 0; mi < MF; ++mi)
#pragma unroll
      for (int nj = 0; nj < 4; ++nj)
#pragma unroll
        for (int kk = 0; kk < 2; ++kk)
          acc[mi][nj] = __builtin_amdgcn_mfma_f32_16x16x32_bf16(afr[mi][kk], bfr[nj][kk], acc[mi][nj], 0, 0, 0);
  }
}

// ---- merged Q/K/V projection GEMM: grid 768 (seg = Q/K/V), 128x128 tiles ----
// Q output pre-scaled by 1/sqrt(HD) = 0.125 (folded out of the attention loop).
__global__ __launch_bounds__(256, 3) void qkv_gemm(const short* __restrict__ xbf, const short* __restrict__ membf,
                                                   const short* __restrict__ wt, short* __restrict__ q_ws,
                                                   float* __restrict__ k_out, short* __restrict__ k_bf,
                                                   float* __restrict__ v_out, short* __restrict__ v_bf) {
  __shared__ short a_lds[128 * 64];
  __shared__ short b_lds[128 * 64];
  const int bid = blockIdx.x;
  const int seg = bid >> 8, rem = bid & 255;
  const int bm = rem & 31, bn = rem >> 5;
  const int tid = threadIdx.x, lane = tid & 63, w = tid >> 6;
  const short* A = (seg == 0) ? xbf : membf;
  const short* B = wt + ((size_t)seg << 20);
  f32x4 acc[4][4];
#pragma unroll
  for (int i = 0; i < 4; ++i)
#pragma unroll
    for (int j = 0; j < 4; ++j) acc[i][j] = (f32x4){0.f, 0.f, 0.f, 0.f};
  mm_loop<128, 4>(A, B, a_lds, b_lds, bm, bn, w, lane, acc);

  const int lm = lane & 15, g4 = (lane >> 4) << 2;
  const int wr = w >> 1, wc = w & 1;
#pragma unroll
  for (int mi = 0; mi < 4; ++mi)
#pragma unroll
    for (int nj = 0; nj < 4; ++nj)
#pragma unroll
      for (int r = 0; r < 4; ++r) {
        const int row = bm * 128 + wr * 64 + mi * 16 + g4 + r;
        const int col = bn * 128 + wc * 64 + nj * 16 + lm;
        const float v = acc[mi][nj][r];
        const int b = row >> 11, t = row & 2047, hh = col >> 6, hd = col & 63;
        const size_t idx = (((size_t)b * NH + hh) * LS + t) * HD + hd;
        if (seg == 0) {
          q_ws[idx] = f2bf(v * 0.125f);
        } else if (seg == 1) {
          k_out[idx] = v;
          k_bf[idx] = f2bf(v);
        } else {
          v_out[idx] = v;
          v_bf[idx] = f2bf(v);
        }
      }
}

// ---- output projection GEMM: 64x128 tiles, grid 512 (2 blocks/CU) ----
__global__ __launch_bounds__(256, 3) void o_gemm(const short* __restrict__ attn_bf, const short* __restrict__ wto,
                                                 float* __restrict__ outp) {
  __shared__ short a_lds[64 * 64];
  __shared__ short b_lds[128 * 64];
  const int bid = blockIdx.x;
  const int bm = bid & 63, bn = bid >> 6;
  const int tid = threadIdx.x, lane = tid & 63, w = tid >> 6;
  f32x4 acc[2][4];
#pragma unroll
  for (int i = 0; i < 2; ++i)
#pragma unroll
    for (int j = 0; j < 4; ++j) acc[i][j] = (f32x4){0.f, 0.f, 0.f, 0.f};
  mm_loop<64, 2>(attn_bf, wto, a_lds, b_lds, bm, bn, w, lane, acc);

  const int lm = lane & 15, g4 = (lane >> 4) << 2;
  const int wr = w >> 1, wc = w & 1;
#pragma unroll
  for (int mi = 0; mi < 2; ++mi)
#pragma unroll
    for (int nj = 0; nj < 4; ++nj)
#pragma unroll
      for (int r = 0; r < 4; ++r) {
        const int row = bm * 64 + wr * 32 + mi * 16 + g4 + r;
        const int col = bn * 128 + wc * 64 + nj * 16 + lm;
        outp[(size_t)row * DIM + col] = acc[mi][nj][r];
      }
}

// ---- fused flash attention v12: b-pair fusion in registers + split-s ----
// 1 block = 64 q-rows of one (h,qt), BOTH batches, HALF the s-range.
// grid = 32 qt x 16 h x 2 s-half = 1024 (4 blk/CU). pe+mask read ONCE per
// (h,t,s) into registers, used for two batch computes. Partial O + LSE out.
__global__ __launch_bounds__(256, 4) void attn_kernel(const short* __restrict__ qw, const short* __restrict__ kbf,
                                                      const short* __restrict__ vbf, const float* __restrict__ pe,
                                                      const float* __restrict__ mask, short* __restrict__ pO,
                                                      float* __restrict__ lse_ws) {
  __shared__ __align__(16) char k_raw[2][8192];   // K tile per batch [s=64][d=64], swizzled
  __shared__ __align__(16) char vt_raw[2][8192];  // V^T tile per batch [d=64][s=64], swizzled
  __shared__ __align__(16) char p_raw[8192];      // P per wave [t=16][s=64], swizzled
  const int bid = blockIdx.x;
  const int qt = bid & 31;
  const int h = (bid >> 5) & 15;
  const int sh = bid >> 9;  // s-half
  const int tid = threadIdx.x, lane = tid & 63, w = tid >> 6;
  const int qbase = qt * 64 + w * 16;
  const int lm = lane & 15, g = lane >> 4, g8 = g << 3, g16 = g << 4, g4 = g << 2;
  constexpr float L2E = 1.4426950408889634f;

  // Q fragments for both batches (B-operand of swapped QK, pre-scaled by 0.125)
  short8 qfr[2][2];
#pragma unroll
  for (int bb = 0; bb < 2; ++bb)
#pragma unroll
    for (int kk = 0; kk < 2; ++kk)
      qfr[bb][kk] = *reinterpret_cast<const short8*>(qw + ((size_t)(bb * NH + h) * LT + qbase + lm) * HD +
                                                     kk * 32 + g8);

  float m_run[2] = {-1e30f, -1e30f}, l_run[2] = {0.f, 0.f};
  f32x4 acc_o[2][4];
#pragma unroll
  for (int bb = 0; bb < 2; ++bb)
#pragma unroll
    for (int dj = 0; dj < 4; ++dj) acc_o[bb][dj] = (f32x4){0.f, 0.f, 0.f, 0.f};

  const int t_lane = qbase + lm;
  const float* pe_row = pe + (size_t)h * LT * LS + (size_t)t_lane * LS;
  const float* mask_row = mask + (size_t)t_lane * LS;

  const int srow = tid >> 2, scol0 = (tid & 3) << 4;  // K staging: 4 lanes per row
  const int kb = scol0 * 2;                           // K staging byte col
  const int vs2 = (lane & 31) << 1;                   // V staging rows
  const int vd0 = (w << 4) + ((lane >> 5) << 3);      // V staging d-slab

  const int s_beg = sh * (LS / 2), s_end = s_beg + (LS / 2);

  for (int s0 = s_beg; s0 < s_end; s0 += 64) {
    // stage K and V^T tiles for both batches, swizzled
#pragma unroll
    for (int bb = 0; bb < 2; ++bb) {
      const size_t bh = (size_t)(bb * NH + h);
      const short* ksrc = kbf + (bh * LS + s0 + srow) * HD + scol0;
      *reinterpret_cast<short8*>(k_raw[bb] + swz(srow, kb)) = *reinterpret_cast<const short8*>(ksrc);
      *reinterpret_cast<short8*>(k_raw[bb] + swz(srow, kb + 16)) = *reinterpret_cast<const short8*>(ksrc + 8);
      const short* vsrc = vbf + (bh * LS + s0 + vs2) * HD + vd0;
      const short8 va = *reinterpret_cast<const short8*>(vsrc);
      const short8 vb = *reinterpret_cast<const short8*>(vsrc + HD);
#pragma unroll
      for (int j = 0; j < 8; ++j) {
        short2v pr = {va[j], vb[j]};
        *reinterpret_cast<short2v*>(vt_raw[bb] + swz(vd0 + j, vs2 * 2)) = pr;
      }
    }
    __syncthreads();

    // pe + mask loaded ONCE into registers; reused by both batch computes
    f32x4 pm[4];
    {
      f32x4 mv[4];
#pragma unroll
      for (int nj = 0; nj < 4; ++nj) {
        const int sb = s0 + nj * 16 + g4;
        pm[nj] = *reinterpret_cast<const f32x4*>(pe_row + sb);
        mv[nj] = *reinterpret_cast<const f32x4*>(mask_row + sb);
      }
#pragma unroll
      for (int nj = 0; nj < 4; ++nj) pm[nj] += mv[nj];
    }

#pragma unroll
    for (int bb = 0; bb < 2; ++bb) {
      // S^T = K Q^T : accs[nj][r] = S[s = s0+nj*16+g4+r][t = qbase+lm] (pre-scaled)
      f32x4 accs[4];
#pragma unroll
      for (int nj = 0; nj < 4; ++nj) {
        accs[nj] = (f32x4){0.f, 0.f, 0.f, 0.f};
#pragma unroll
        for (int kk = 0; kk < 2; ++kk) {
          const short8 kfr = *reinterpret_cast<const short8*>(k_raw[bb] + swz(nj * 16 + lm, kk * 64 + g16));
          accs[nj] = __builtin_amdgcn_mfma_f32_16x16x32_bf16(kfr, qfr[bb][kk], accs[nj], 0, 0, 0);
        }
      }

#pragma unroll
      for (int nj = 0; nj < 4; ++nj)
#pragma unroll
        for (int r = 0; r < 4; ++r) accs[nj][r] += pm[nj][r];

      float mx = accs[0][0];
#pragma unroll
      for (int nj = 0; nj < 4; ++nj)
#pragma unroll
        for (int r = 0; r < 4; ++r) mx = fmaxf(mx, accs[nj][r]);
      mx = fmaxf(mx, __shfl_xor(mx, 16));
      mx = fmaxf(mx, __shfl_xor(mx, 32));
      const float mnew = fmaxf(m_run[bb], mx);
      const float nm = mnew * L2E;
      float rs = 0.f;
#pragma unroll
      for (int nj = 0; nj < 4; ++nj)
#pragma unroll
        for (int r = 0; r < 4; ++r) {
          const float p = exp2f(fmaf(accs[nj][r], L2E, -nm));
          accs[nj][r] = p;
          rs += p;
        }
      rs += __shfl_xor(rs, 16);
      rs += __shfl_xor(rs, 32);
      const float sc = exp2f(fmaf(m_run[bb], L2E, -nm));
      l_run[bb] = l_run[bb] * sc + rs;
      m_run[bb] = mnew;

      // write P[t][s] (wave-private region; in-order DS ops, no barrier)
#pragma unroll
      for (int nj = 0; nj < 4; ++nj) {
        short4v pk = {f2bf(accs[nj][0]), f2bf(accs[nj][1]), f2bf(accs[nj][2]), f2bf(accs[nj][3])};
        *reinterpret_cast<short4v*>(p_raw + (w << 11) + swz(lm, nj * 32 + g * 8)) = pk;
      }
      // redistribute per-t rescale factor via shuffles (t=lm layout -> t=g4+r layout)
      float sc4[4];
#pragma unroll
      for (int r = 0; r < 4; ++r) sc4[r] = __shfl(sc, g4 + r);
#pragma unroll
      for (int dj = 0; dj < 4; ++dj)
#pragma unroll
        for (int r = 0; r < 4; ++r) acc_o[bb][dj][r] *= sc4[r];

      // O += P V
#pragma unroll
      for (int kk = 0; kk < 2; ++kk) {
        const short8 pfr = *reinterpret_cast<const short8*>(p_raw + (w << 11) + swz(lm, kk * 64 + g16));
#pragma unroll
        for (int dj = 0; dj < 4; ++dj) {
          const short8 vfr = *reinterpret_cast<const short8*>(vt_raw[bb] + swz(dj * 16 + lm, kk * 64 + g16));
          acc_o[bb][dj] = __builtin_amdgcn_mfma_f32_16x16x32_bf16(pfr, vfr, acc_o[bb][dj], 0, 0, 0);
        }
      }
    }
    __syncthreads();  // protect k_raw/vt_raw before next stage
  }

  // epilogue: normalized partial O (bf16) + LSE (log2 units) per batch
#pragma unroll
  for (int bb = 0; bb < 2; ++bb) {
    if (g == 0) lse_ws[((size_t)(sh * NB + bb) * NH + h) * LT + t_lane] = fmaf(m_run[bb], L2E, __log2f(l_run[bb]));
    float l4[4];
#pragma unroll
    for (int r = 0; r < 4; ++r) l4[r] = __shfl(l_run[bb], g4 + r);
#pragma unroll
    for (int r = 0; r < 4; ++r) {
      const float inv = 1.f / l4[r];
      const int t = qbase + g4 + r;
      const size_t prow = ((size_t)(sh * NB + bb) * NH + h) * LT + t;
#pragma unroll
      for (int dj = 0; dj < 4; ++dj) {
        const int d = dj * 16 + lm;
        pO[prow * HD + d] = f2bf(acc_o[bb][dj][r] * inv);
      }
    }
  }
}

// ---- combine: merge the two s-half partials -> attn_ws [B, LT, H*HD] bf16 ----
__global__ __launch_bounds__(256) void combine_kernel(const short* __restrict__ pO,
                                                      const float* __restrict__ lse,
                                                      short* __restrict__ aout) {
  const int gid = blockIdx.x * 256 + threadIdx.x;  // 524288 threads
  const int row = gid >> 3;                        // (b*NH+h)*LT + t, 65536 rows
  const int d0 = (gid & 7) << 3;
  const int b = row >> 15;
  const int h = (row >> 11) & 15;
  const int t = row & 2047;
  const size_t r0 = (size_t)row;
  const size_t r1 = (size_t)row + (size_t)NB * NH * LT;
  const float l0 = lse[r0], l1 = lse[r1];
  const float mm = fmaxf(l0, l1);
  float w0 = exp2f(l0 - mm), w1 = exp2f(l1 - mm);
  const float inv = 1.f / (w0 + w1);
  w0 *= inv;
  w1 *= inv;
  const short8 o0 = *reinterpret_cast<const short8*>(pO + r0 * HD + d0);
  const short8 o1 = *reinterpret_cast<const short8*>(pO + r1 * HD + d0);
  short8 out;
#pragma unroll
  for (int j = 0; j < 8; ++j) out[j] = f2bf(b2f(o0[j]) * w0 + b2f(o1[j]) * w1);
  *reinterpret_cast<short8*>(aout + ((size_t)b * LT + t) * DIM + h * HD + d0) = out;
}

extern "C" void kernel_launch(void* const* d_in, const int* in_sizes, int n_in, void* d_out, int out_size,
                              void* d_ws, size_t ws_size, hipStream_t stream) {
  (void)in_sizes;
  (void)n_in;
  (void)out_size;
  (void)ws_size;
  const float* x = (const float*)d_in[0];
  const float* memory = (const float*)d_in[1];
  const float* pe = (const float*)d_in[2];
  const float* mask = (const float*)d_in[3];
  const float* Wq = (const float*)d_in[4];
  const float* Wk = (const float*)d_in[5];
  const float* Wv = (const float*)d_in[6];
  const float* Wo = (const float*)d_in[7];
  float* outp = (float*)d_out;
  float* k_out = outp + (size_t)NB * NH * LS * HD;
  float* v_out = k_out + (size_t)NB * NH * LS * HD;
  char* ws = (char*)d_ws;
  short* q_ws = (short*)ws;                      //  8 MiB: Q bf16 [B,H,LT,HD] (pre-scaled by 0.125)
  short* attn_ws = (short*)(ws + (8u << 20));    //  8 MiB: attn out bf16 [B,LT,D]
  short* wt = (short*)(ws + (16u << 20));        //  8 MiB: 4x Wt bf16 [N][K]; Wq^T region dead post-qkv
  short* k_bf = (short*)(ws + (24u << 20));      //  8 MiB: K bf16 [B,H,LS,HD]
  short* v_bf = (short*)(ws + (32u << 20));      //  8 MiB: V bf16 [B,H,LS,HD]
  short* xbf = (short*)(ws + (40u << 20));       //  8 MiB: x bf16 (dead post-qkv)
  short* membf = (short*)(ws + (48u << 20));     //  8 MiB: memory bf16 (dead post-qkv)
  // attn-phase reuse of dead regions:
  short* pO = xbf;                               // 16 MiB: partial O bf16 [half][B][H][LT][HD]
  float* lse_ws = (float*)(ws + (16u << 20));    // 0.5 MiB: LSE fp32 [half][B][H][LT] (Wq^T region, dead)

  prep_kernel<<<dim3(3072), dim3(256), 0, stream>>>(x, memory, Wq, Wk, Wv, Wo, wt, xbf, membf);
  qkv_gemm<<<dim3(768), dim3(256), 0, stream>>>(xbf, membf, wt, q_ws, k_out, k_bf, v_out, v_bf);
  attn_kernel<<<dim3(1024), dim3(256), 0, stream>>>(q_ws, k_bf, v_bf, pe, mask, pO, lse_ws);
  combine_kernel<<<dim3(2048), dim3(256), 0, stream>>>(pO, lse_ws, attn_ws);
  o_gemm<<<dim3(512), dim3(256), 0, stream>>>(attn_ws, wt + (3u << 20), outp);
}